// Round 6
// baseline (113.152 us; speedup 1.0000x reference)
//
#include <hip/hip_runtime.h>
#include <hip/hip_bf16.h>

#define CS 384
#define CH 32
#define CZ 128
#define LL 384
#define NL 1536   // N*L
#define EPS 1e-5f

typedef float v2f __attribute__((ext_vector_type(2)));
typedef float v4f __attribute__((ext_vector_type(4)));

// ---------------- Kernel 1: LayerNorm + A = sn@W1+b1, B = sn@W2+b2 ------------
__global__ __launch_bounds__(128) void k_ln_ab(
    const float* __restrict__ s, const float* __restrict__ g, const float* __restrict__ be,
    const float* __restrict__ W1, const float* __restrict__ b1,
    const float* __restrict__ W2, const float* __restrict__ b2,
    float* __restrict__ A, float* __restrict__ B)
{
    const int row = blockIdx.x;
    const int t   = threadIdx.x;
    const int wid = t >> 6, lane = t & 63;
    const float* srow = s + (size_t)row * CS;

    __shared__ float sn[CS];
    __shared__ float red[2];
    __shared__ float part[128];

    float x0 = srow[t], x1 = srow[t + 128], x2 = srow[t + 256];

    // mean
    float p = x0 + x1 + x2;
    #pragma unroll
    for (int o = 32; o > 0; o >>= 1) p += __shfl_down(p, o);
    if (lane == 0) red[wid] = p;
    __syncthreads();
    const float mu = (red[0] + red[1]) * (1.0f / CS);
    __syncthreads();

    // variance
    float d0 = x0 - mu, d1 = x1 - mu, d2 = x2 - mu;
    float q = d0 * d0 + d1 * d1 + d2 * d2;
    #pragma unroll
    for (int o = 32; o > 0; o >>= 1) q += __shfl_down(q, o);
    if (lane == 0) red[wid] = q;
    __syncthreads();
    const float var = (red[0] + red[1]) * (1.0f / CS);
    const float rstd = rsqrtf(var + EPS);

    sn[t]       = d0 * rstd * g[t]       + be[t];
    sn[t + 128] = d1 * rstd * g[t + 128] + be[t + 128];
    sn[t + 256] = d2 * rstd * g[t + 256] + be[t + 256];
    __syncthreads();

    // matvec: all 128 threads. t -> (half = t>>6, mat = (t>>5)&1, h = t&31)
    {
        const int h    = t & 31;
        const int mat  = (t >> 5) & 1;
        const int half = t >> 6;
        const float* W = mat ? W2 : W1;
        float acc = 0.0f;
        const int c0 = half * (CS / 2);
        #pragma unroll 8
        for (int c = c0; c < c0 + CS / 2; ++c)
            acc += sn[c] * W[c * CH + h];
        part[t] = acc;
    }
    __syncthreads();
    if (t < 64) {
        const int h   = t & 31;
        const int mat = t >> 5;
        const float v = part[t] + part[t + 64] + (mat ? b2[h] : b1[h]);
        (mat ? B : A)[(size_t)row * CH + h] = v;
    }
}

// ---------------- Kernel 2: M[r,d,z] = sum_c A[r,c] * Wo[c,d,z] --------------
// GEMM: [NL,32] x [32,4096] -> [NL,4096]; 4 rows/block, 384 blocks.
__global__ __launch_bounds__(256) void k_m(
    const float* __restrict__ A, const float* __restrict__ Wo, float* __restrict__ M)
{
    const int t  = threadIdx.x;
    const int r0 = blockIdx.x * 4;
    __shared__ float Al[4][CH];
    if (t < 128) Al[t >> 5][t & 31] = A[(size_t)(r0 + (t >> 5)) * CH + (t & 31)];
    __syncthreads();

    const v4f* Wo4 = (const v4f*)Wo;      // 1024 float4 per c-row
    v4f*       M4  = (v4f*)M;

    for (int g4 = t; g4 < 1024; g4 += 256) {
        v4f acc[4];
        #pragma unroll
        for (int r = 0; r < 4; ++r) acc[r] = (v4f)(0.f);
        #pragma unroll 8
        for (int c = 0; c < CH; ++c) {
            const v4f wv = Wo4[(size_t)c * 1024 + g4];
            #pragma unroll
            for (int r = 0; r < 4; ++r)
                acc[r] += Al[r][c] * wv;
        }
        #pragma unroll
        for (int r = 0; r < 4; ++r)
            M4[(size_t)(r0 + r) * 1024 + g4] = acc[r];
    }
}

// ---------------- Kernel 3: out[r,j,z] = sum_d B[n,j,d]*M[r,d,z] + bo[z] -----
// One block (4 waves) per r. Whole B_n panel (384x32 = 48 KB) staged in LDS
// once per block (from L2; 384 blocks share each B_n). j-loop touches VMEM
// only for the output store -> stores never gate a load's vmcnt wait; b-rows
// come from LDS broadcast (wave-uniform ds_read_b128, conflict-free).
// Wave w owns j in [96w, 96w+96); thread tz owns z-pair; m[32] v2f in regs.
__global__ __launch_bounds__(256, 3) void k_out(
    const float* __restrict__ B, const float* __restrict__ M,
    const float* __restrict__ bo, float* __restrict__ out)
{
    const int r  = blockIdx.x;
    const int t  = threadIdx.x;
    const int tz = t & 63;          // z = 2*tz
    const int w  = t >> 6;          // wave id 0..3
    const int n  = r / LL;

    __shared__ float Bl[LL * CH];   // 48 KB

    // cooperative stage of B_n into LDS (3072 float4, 12 per thread)
    {
        const v4f* Bn4 = (const v4f*)(B + (size_t)n * LL * CH);
        v4f* Bl4 = (v4f*)Bl;
        #pragma unroll
        for (int i = 0; i < 12; ++i)
            Bl4[t + i * 256] = Bn4[t + i * 256];
    }

    v2f m[CH];
    {
        const v2f* Mr = (const v2f*)(M + (size_t)r * (CH * CZ));
        #pragma unroll
        for (int d = 0; d < CH; ++d) m[d] = Mr[d * 64 + tz];
    }
    const v2f bz = ((const v2f*)bo)[tz];

    __syncthreads();

    v2f* outr = (v2f*)(out + (size_t)r * LL * CZ);
    const int j0 = w * 96;

    #pragma unroll 2
    for (int jj = 0; jj < 96; ++jj) {
        const int j = j0 + jj;
        const v4f* br = (const v4f*)&Bl[j * CH];   // wave-uniform LDS address
        v4f b[8];
        #pragma unroll
        for (int q = 0; q < 8; ++q) b[q] = br[q];

        v2f acc = bz;
        #pragma unroll
        for (int q = 0; q < 8; ++q) {
            acc += b[q].x * m[4*q+0];
            acc += b[q].y * m[4*q+1];
            acc += b[q].z * m[4*q+2];
            acc += b[q].w * m[4*q+3];
        }
        outr[(size_t)j * 64 + tz] = acc;
    }
}

extern "C" void kernel_launch(void* const* d_in, const int* in_sizes, int n_in,
                              void* d_out, int out_size, void* d_ws, size_t ws_size,
                              hipStream_t stream) {
    const float* s  = (const float*)d_in[0];
    const float* g  = (const float*)d_in[1];
    const float* be = (const float*)d_in[2];
    const float* W1 = (const float*)d_in[3];
    const float* b1 = (const float*)d_in[4];
    const float* W2 = (const float*)d_in[5];
    const float* b2 = (const float*)d_in[6];
    const float* Wo = (const float*)d_in[7];
    const float* bo = (const float*)d_in[8];
    float* out = (float*)d_out;

    const size_t nA = (size_t)NL * CH;
    const size_t nM = (size_t)NL * CH * CZ;
    if (ws_size < (nA * 2 + nM) * sizeof(float)) return;  // fail visibly, no UB

    float* A  = (float*)d_ws;
    float* Bm = A + nA;
    float* M  = Bm + nA;

    k_ln_ab<<<NL, 128, 0, stream>>>(s, g, be, W1, b1, W2, b2, A, Bm);
    k_m   <<<NL / 4, 256, 0, stream>>>(A, Wo, M);
    k_out <<<NL, 256, 0, stream>>>(Bm, M, bo, out);
}

// Round 7
// 111.114 us; speedup vs baseline: 1.0183x; 1.0183x over previous
//
#include <hip/hip_runtime.h>
#include <hip/hip_bf16.h>

#define CS 384
#define CH 32
#define CZ 128
#define LL 384
#define NL 1536   // N*L
#define EPS 1e-5f

typedef float v2f __attribute__((ext_vector_type(2)));
typedef float v4f __attribute__((ext_vector_type(4)));

// ---------------- Kernel 1: LayerNorm + A = sn@W1+b1, B = sn@W2+b2 ------------
__global__ __launch_bounds__(128) void k_ln_ab(
    const float* __restrict__ s, const float* __restrict__ g, const float* __restrict__ be,
    const float* __restrict__ W1, const float* __restrict__ b1,
    const float* __restrict__ W2, const float* __restrict__ b2,
    float* __restrict__ A, float* __restrict__ B)
{
    const int row = blockIdx.x;
    const int t   = threadIdx.x;
    const int wid = t >> 6, lane = t & 63;
    const float* srow = s + (size_t)row * CS;

    __shared__ float sn[CS];
    __shared__ float red[2];
    __shared__ float part[128];

    float x0 = srow[t], x1 = srow[t + 128], x2 = srow[t + 256];

    // mean
    float p = x0 + x1 + x2;
    #pragma unroll
    for (int o = 32; o > 0; o >>= 1) p += __shfl_down(p, o);
    if (lane == 0) red[wid] = p;
    __syncthreads();
    const float mu = (red[0] + red[1]) * (1.0f / CS);
    __syncthreads();

    // variance
    float d0 = x0 - mu, d1 = x1 - mu, d2 = x2 - mu;
    float q = d0 * d0 + d1 * d1 + d2 * d2;
    #pragma unroll
    for (int o = 32; o > 0; o >>= 1) q += __shfl_down(q, o);
    if (lane == 0) red[wid] = q;
    __syncthreads();
    const float var = (red[0] + red[1]) * (1.0f / CS);
    const float rstd = rsqrtf(var + EPS);

    sn[t]       = d0 * rstd * g[t]       + be[t];
    sn[t + 128] = d1 * rstd * g[t + 128] + be[t + 128];
    sn[t + 256] = d2 * rstd * g[t + 256] + be[t + 256];
    __syncthreads();

    // matvec: all 128 threads. t -> (half = t>>6, mat = (t>>5)&1, h = t&31)
    {
        const int h    = t & 31;
        const int mat  = (t >> 5) & 1;
        const int half = t >> 6;
        const float* W = mat ? W2 : W1;
        float acc = 0.0f;
        const int c0 = half * (CS / 2);
        #pragma unroll 8
        for (int c = c0; c < c0 + CS / 2; ++c)
            acc += sn[c] * W[c * CH + h];
        part[t] = acc;
    }
    __syncthreads();
    if (t < 64) {
        const int h   = t & 31;
        const int mat = t >> 5;
        const float v = part[t] + part[t + 64] + (mat ? b2[h] : b1[h]);
        (mat ? B : A)[(size_t)row * CH + h] = v;
    }
}

// ---------------- Kernel 2: M[r,d,z] = sum_c A[r,c] * Wo[c,d,z] --------------
// GEMM: [NL,32] x [32,4096] -> [NL,4096]; 4 rows/block, 384 blocks.
__global__ __launch_bounds__(256) void k_m(
    const float* __restrict__ A, const float* __restrict__ Wo, float* __restrict__ M)
{
    const int t  = threadIdx.x;
    const int r0 = blockIdx.x * 4;
    __shared__ float Al[4][CH];
    if (t < 128) Al[t >> 5][t & 31] = A[(size_t)(r0 + (t >> 5)) * CH + (t & 31)];
    __syncthreads();

    const v4f* Wo4 = (const v4f*)Wo;      // 1024 float4 per c-row
    v4f*       M4  = (v4f*)M;

    for (int g4 = t; g4 < 1024; g4 += 256) {
        v4f acc[4];
        #pragma unroll
        for (int r = 0; r < 4; ++r) acc[r] = (v4f)(0.f);
        #pragma unroll 8
        for (int c = 0; c < CH; ++c) {
            const v4f wv = Wo4[(size_t)c * 1024 + g4];
            #pragma unroll
            for (int r = 0; r < 4; ++r)
                acc[r] += Al[r][c] * wv;
        }
        #pragma unroll
        for (int r = 0; r < 4; ++r)
            M4[(size_t)(r0 + r) * 1024 + g4] = acc[r];
    }
}

// ---------------- Kernel 3: out[r,j,z] = sum_d B[n,j,d]*M[r,d,z] + bo[z] -----
// One block (4 waves) per r; B_n panel (48 KB) in LDS. Half-wave split:
// lanes 0-31 compute row j, lanes 32-63 row j+1; each lane owns a z-QUAD
// (m[32] v4f = 128 VGPR). Per iter: 8 ds_read_b128 serve TWO rows (2-way
// same-bank = free), 64 pk-FMAs, one dwordx4 store -> 1024 B contiguous per
// wave-store (fill-kernel width).
__global__ __launch_bounds__(256, 2) void k_out(
    const float* __restrict__ B, const float* __restrict__ M,
    const float* __restrict__ bo, float* __restrict__ out)
{
    const int r = blockIdx.x;
    const int t = threadIdx.x;
    const int q = t & 31;           // z-quad 0..31  (z = 4q..4q+3)
    const int h = (t >> 5) & 1;     // half-wave row offset
    const int w = t >> 6;           // wave 0..3
    const int n = r / LL;

    __shared__ float Bl[LL * CH];   // 48 KB

    // cooperative stage of B_n into LDS (3072 v4f, 12 per thread)
    {
        const v4f* Bn4 = (const v4f*)(B + (size_t)n * LL * CH);
        v4f* Bl4 = (v4f*)Bl;
        #pragma unroll
        for (int i = 0; i < 12; ++i)
            Bl4[t + i * 256] = Bn4[t + i * 256];
    }

    v4f m[CH];
    {
        const v4f* Mr = (const v4f*)(M + (size_t)r * (CH * CZ));  // 32 v4f per d
        #pragma unroll
        for (int d = 0; d < CH; ++d) m[d] = Mr[d * 32 + q];
    }
    const v4f bz = ((const v4f*)bo)[q];

    __syncthreads();

    v4f* outr = (v4f*)(out + (size_t)r * LL * CZ);   // 32 v4f per j-row
    const int j0 = w * 96;

    #pragma unroll 2
    for (int jj = 0; jj < 96; jj += 2) {
        const int j = j0 + jj + h;                    // this lane's row
        const v4f* br = (const v4f*)&Bl[j * CH];
        v4f b[8];
        #pragma unroll
        for (int k = 0; k < 8; ++k) b[k] = br[k];

        v4f acc = bz;
        #pragma unroll
        for (int k = 0; k < 8; ++k) {
            acc += b[k].x * m[4*k+0];
            acc += b[k].y * m[4*k+1];
            acc += b[k].z * m[4*k+2];
            acc += b[k].w * m[4*k+3];
        }
        outr[(size_t)j * 32 + q] = acc;
    }
}

extern "C" void kernel_launch(void* const* d_in, const int* in_sizes, int n_in,
                              void* d_out, int out_size, void* d_ws, size_t ws_size,
                              hipStream_t stream) {
    const float* s  = (const float*)d_in[0];
    const float* g  = (const float*)d_in[1];
    const float* be = (const float*)d_in[2];
    const float* W1 = (const float*)d_in[3];
    const float* b1 = (const float*)d_in[4];
    const float* W2 = (const float*)d_in[5];
    const float* b2 = (const float*)d_in[6];
    const float* Wo = (const float*)d_in[7];
    const float* bo = (const float*)d_in[8];
    float* out = (float*)d_out;

    const size_t nA = (size_t)NL * CH;
    const size_t nM = (size_t)NL * CH * CZ;
    if (ws_size < (nA * 2 + nM) * sizeof(float)) return;  // fail visibly, no UB

    float* A  = (float*)d_ws;
    float* Bm = A + nA;
    float* M  = Bm + nA;

    k_ln_ab<<<NL, 128, 0, stream>>>(s, g, be, W1, b1, W2, b2, A, Bm);
    k_m   <<<NL / 4, 256, 0, stream>>>(A, Wo, M);
    k_out <<<NL, 256, 0, stream>>>(Bm, M, bo, out);
}

// Round 8
// 107.008 us; speedup vs baseline: 1.0574x; 1.0384x over previous
//
#include <hip/hip_runtime.h>
#include <hip/hip_bf16.h>

#define CS 384
#define CH 32
#define CZ 128
#define LL 384
#define NL 1536   // N*L
#define EPS 1e-5f

typedef float v2f  __attribute__((ext_vector_type(2)));
typedef float v4f  __attribute__((ext_vector_type(4)));
typedef float v16f __attribute__((ext_vector_type(16)));

// ---------------- Kernel 1: LayerNorm + A = sn@W1+b1, B = sn@W2+b2 ------------
__global__ __launch_bounds__(128) void k_ln_ab(
    const float* __restrict__ s, const float* __restrict__ g, const float* __restrict__ be,
    const float* __restrict__ W1, const float* __restrict__ b1,
    const float* __restrict__ W2, const float* __restrict__ b2,
    float* __restrict__ A, float* __restrict__ B)
{
    const int row = blockIdx.x;
    const int t   = threadIdx.x;
    const int wid = t >> 6, lane = t & 63;
    const float* srow = s + (size_t)row * CS;

    __shared__ float sn[CS];
    __shared__ float red[2];
    __shared__ float part[128];

    float x0 = srow[t], x1 = srow[t + 128], x2 = srow[t + 256];

    // mean
    float p = x0 + x1 + x2;
    #pragma unroll
    for (int o = 32; o > 0; o >>= 1) p += __shfl_down(p, o);
    if (lane == 0) red[wid] = p;
    __syncthreads();
    const float mu = (red[0] + red[1]) * (1.0f / CS);
    __syncthreads();

    // variance
    float d0 = x0 - mu, d1 = x1 - mu, d2 = x2 - mu;
    float q = d0 * d0 + d1 * d1 + d2 * d2;
    #pragma unroll
    for (int o = 32; o > 0; o >>= 1) q += __shfl_down(q, o);
    if (lane == 0) red[wid] = q;
    __syncthreads();
    const float var = (red[0] + red[1]) * (1.0f / CS);
    const float rstd = rsqrtf(var + EPS);

    sn[t]       = d0 * rstd * g[t]       + be[t];
    sn[t + 128] = d1 * rstd * g[t + 128] + be[t + 128];
    sn[t + 256] = d2 * rstd * g[t + 256] + be[t + 256];
    __syncthreads();

    // matvec: all 128 threads. t -> (half = t>>6, mat = (t>>5)&1, h = t&31)
    {
        const int h    = t & 31;
        const int mat  = (t >> 5) & 1;
        const int half = t >> 6;
        const float* W = mat ? W2 : W1;
        float acc = 0.0f;
        const int c0 = half * (CS / 2);
        #pragma unroll 8
        for (int c = c0; c < c0 + CS / 2; ++c)
            acc += sn[c] * W[c * CH + h];
        part[t] = acc;
    }
    __syncthreads();
    if (t < 64) {
        const int h   = t & 31;
        const int mat = t >> 5;
        const float v = part[t] + part[t + 64] + (mat ? b2[h] : b1[h]);
        (mat ? B : A)[(size_t)row * CH + h] = v;
    }
}

// ---------------- Kernel 2: M[r,d,z] = sum_c A[r,c] * Wo[c,d,z] --------------
// GEMM: [NL,32] x [32,4096] -> [NL,4096]; 4 rows/block, 384 blocks.
__global__ __launch_bounds__(256) void k_m(
    const float* __restrict__ A, const float* __restrict__ Wo, float* __restrict__ M)
{
    const int t  = threadIdx.x;
    const int r0 = blockIdx.x * 4;
    __shared__ float Al[4][CH];
    if (t < 128) Al[t >> 5][t & 31] = A[(size_t)(r0 + (t >> 5)) * CH + (t & 31)];
    __syncthreads();

    const v4f* Wo4 = (const v4f*)Wo;      // 1024 float4 per c-row
    v4f*       M4  = (v4f*)M;

    for (int g4 = t; g4 < 1024; g4 += 256) {
        v4f acc[4];
        #pragma unroll
        for (int r = 0; r < 4; ++r) acc[r] = (v4f)(0.f);
        #pragma unroll 8
        for (int c = 0; c < CH; ++c) {
            const v4f wv = Wo4[(size_t)c * 1024 + g4];
            #pragma unroll
            for (int r = 0; r < 4; ++r)
                acc[r] += Al[r][c] * wv;
        }
        #pragma unroll
        for (int r = 0; r < 4; ++r)
            M4[(size_t)(r0 + r) * 1024 + g4] = acc[r];
    }
}

// ---------------- Kernel 3: out[r,j,z] = sum_d B[n,j,d]*M[r,d,z] + bo[z] -----
// Grid (NL, 4): 1-wave blocks; wave owns r and a 96-row j-chunk. The b-row is
// loaded into SGPRs via s_load_dwordx16 (address uniform by construction:
// blockIdx + loop constant only). Each FMA reads b from an SGPR (free
// broadcast) x m from VGPRs -> zero per-lane broadcast bandwidth; no LDS.
// SMEM returns can be out of order -> only lgkmcnt(0) waits; 1-row-ahead
// software pipeline (issue AFTER wait, compute covers the latency).
#define LOAD2(X0, X1, P) \
    asm volatile("s_load_dwordx16 %0, %2, 0x0\n\t" \
                 "s_load_dwordx16 %1, %2, 0x40" \
                 : "=&s"(X0), "=&s"(X1) : "s"(P))
#define WAIT2(X0, X1) \
    asm volatile("s_waitcnt lgkmcnt(0)" : "+s"(X0), "+s"(X1) :: "memory")

__global__ __launch_bounds__(64, 4) void k_out(
    const float* __restrict__ B, const float* __restrict__ M,
    const float* __restrict__ bo, float* __restrict__ out)
{
    const int r  = blockIdx.x;
    const int jc = blockIdx.y;          // 0..3, 96 rows each
    const int tz = threadIdx.x;         // 0..63; z-pair = 2*tz
    const int n  = r / LL;

    v2f m[CH];
    {
        const v2f* Mr = (const v2f*)(M + (size_t)r * (CH * CZ));
        #pragma unroll
        for (int d = 0; d < CH; ++d) m[d] = Mr[d * 64 + tz];
    }
    const v2f bz = ((const v2f*)bo)[tz];

    const float* Bj = B + ((size_t)n * LL + jc * 96) * CH;
    v2f* outr = (v2f*)(out + (size_t)r * LL * CZ) + (size_t)(jc * 96) * 64;

    v16f bA0, bA1, bB0, bB1;
    LOAD2(bA0, bA1, Bj);                // prologue: row 0 -> A

    #define FMASTORE(V0, V1, ROW) do { \
        v2f a0 = bz, a1 = (v2f)(0.f); \
        _Pragma("unroll") \
        for (int k = 0; k < 16; ++k) { \
            a0 += V0[k] * m[k]; \
            a1 += V1[k] * m[16 + k]; \
        } \
        outr[(size_t)(ROW) * 64 + tz] = a0 + a1; \
    } while (0)

    for (int jj = 0; jj < 96; jj += 2) {
        // even row: A ready -> issue jj+1 into B, compute jj from A
        WAIT2(bA0, bA1);
        const float* p1 = Bj + (size_t)(jj + 1) * CH;
        LOAD2(bB0, bB1, p1);
        FMASTORE(bA0, bA1, jj);
        // odd row: B ready -> issue jj+2 into A, compute jj+1 from B
        WAIT2(bB0, bB1);
        const float* p2 = (jj + 2 < 96) ? (Bj + (size_t)(jj + 2) * CH) : Bj;
        LOAD2(bA0, bA1, p2);
        FMASTORE(bB0, bB1, jj + 1);
    }
    #undef FMASTORE
}

extern "C" void kernel_launch(void* const* d_in, const int* in_sizes, int n_in,
                              void* d_out, int out_size, void* d_ws, size_t ws_size,
                              hipStream_t stream) {
    const float* s  = (const float*)d_in[0];
    const float* g  = (const float*)d_in[1];
    const float* be = (const float*)d_in[2];
    const float* W1 = (const float*)d_in[3];
    const float* b1 = (const float*)d_in[4];
    const float* W2 = (const float*)d_in[5];
    const float* b2 = (const float*)d_in[6];
    const float* Wo = (const float*)d_in[7];
    const float* bo = (const float*)d_in[8];
    float* out = (float*)d_out;

    const size_t nA = (size_t)NL * CH;
    const size_t nM = (size_t)NL * CH * CZ;
    if (ws_size < (nA * 2 + nM) * sizeof(float)) return;  // fail visibly, no UB

    float* A  = (float*)d_ws;
    float* Bm = A + nA;
    float* M  = Bm + nA;

    k_ln_ab<<<NL, 128, 0, stream>>>(s, g, be, W1, b1, W2, b2, A, Bm);
    k_m   <<<NL / 4, 256, 0, stream>>>(A, Wo, M);
    dim3 gout(NL, 4);
    k_out <<<gout, 64, 0, stream>>>(Bm, M, bo, out);
}

// Round 9
// 103.962 us; speedup vs baseline: 1.0884x; 1.0293x over previous
//
#include <hip/hip_runtime.h>
#include <hip/hip_bf16.h>

#define CS 384
#define CH 32
#define CZ 128
#define LL 384
#define NL 1536   // N*L
#define EPS 1e-5f

typedef float v2f  __attribute__((ext_vector_type(2)));
typedef float v4f  __attribute__((ext_vector_type(4)));
typedef float v16f __attribute__((ext_vector_type(16)));

// ---------------- Kernel 1: LayerNorm + A = sn@W1+b1, B = sn@W2+b2 ------------
__global__ __launch_bounds__(128) void k_ln_ab(
    const float* __restrict__ s, const float* __restrict__ g, const float* __restrict__ be,
    const float* __restrict__ W1, const float* __restrict__ b1,
    const float* __restrict__ W2, const float* __restrict__ b2,
    float* __restrict__ A, float* __restrict__ B)
{
    const int row = blockIdx.x;
    const int t   = threadIdx.x;
    const int wid = t >> 6, lane = t & 63;
    const float* srow = s + (size_t)row * CS;

    __shared__ float sn[CS];
    __shared__ float red[2];
    __shared__ float part[128];

    float x0 = srow[t], x1 = srow[t + 128], x2 = srow[t + 256];

    // mean
    float p = x0 + x1 + x2;
    #pragma unroll
    for (int o = 32; o > 0; o >>= 1) p += __shfl_down(p, o);
    if (lane == 0) red[wid] = p;
    __syncthreads();
    const float mu = (red[0] + red[1]) * (1.0f / CS);
    __syncthreads();

    // variance
    float d0 = x0 - mu, d1 = x1 - mu, d2 = x2 - mu;
    float q = d0 * d0 + d1 * d1 + d2 * d2;
    #pragma unroll
    for (int o = 32; o > 0; o >>= 1) q += __shfl_down(q, o);
    if (lane == 0) red[wid] = q;
    __syncthreads();
    const float var = (red[0] + red[1]) * (1.0f / CS);
    const float rstd = rsqrtf(var + EPS);

    sn[t]       = d0 * rstd * g[t]       + be[t];
    sn[t + 128] = d1 * rstd * g[t + 128] + be[t + 128];
    sn[t + 256] = d2 * rstd * g[t + 256] + be[t + 256];
    __syncthreads();

    // matvec: all 128 threads. t -> (half = t>>6, mat = (t>>5)&1, h = t&31)
    {
        const int h    = t & 31;
        const int mat  = (t >> 5) & 1;
        const int half = t >> 6;
        const float* W = mat ? W2 : W1;
        float acc = 0.0f;
        const int c0 = half * (CS / 2);
        #pragma unroll 8
        for (int c = c0; c < c0 + CS / 2; ++c)
            acc += sn[c] * W[c * CH + h];
        part[t] = acc;
    }
    __syncthreads();
    if (t < 64) {
        const int h   = t & 31;
        const int mat = t >> 5;
        const float v = part[t] + part[t + 64] + (mat ? b2[h] : b1[h]);
        (mat ? B : A)[(size_t)row * CH + h] = v;
    }
}

// ---------------- Kernel 2: M[r,d,z] = sum_c A[r,c] * Wo[c,d,z] --------------
// GEMM: [NL,32] x [32,4096] -> [NL,4096]; 4 rows/block, 384 blocks.
__global__ __launch_bounds__(256) void k_m(
    const float* __restrict__ A, const float* __restrict__ Wo, float* __restrict__ M)
{
    const int t  = threadIdx.x;
    const int r0 = blockIdx.x * 4;
    __shared__ float Al[4][CH];
    if (t < 128) Al[t >> 5][t & 31] = A[(size_t)(r0 + (t >> 5)) * CH + (t & 31)];
    __syncthreads();

    const v4f* Wo4 = (const v4f*)Wo;      // 1024 float4 per c-row
    v4f*       M4  = (v4f*)M;

    for (int g4 = t; g4 < 1024; g4 += 256) {
        v4f acc[4];
        #pragma unroll
        for (int r = 0; r < 4; ++r) acc[r] = (v4f)(0.f);
        #pragma unroll 8
        for (int c = 0; c < CH; ++c) {
            const v4f wv = Wo4[(size_t)c * 1024 + g4];
            #pragma unroll
            for (int r = 0; r < 4; ++r)
                acc[r] += Al[r][c] * wv;
        }
        #pragma unroll
        for (int r = 0; r < 4; ++r)
            M4[(size_t)(r0 + r) * 1024 + g4] = acc[r];
    }
}

// ---------------- Kernel 3: out[r,j,z] = sum_d B[n,j,d]*M[r,d,z] + bo[z] -----
// Half-waves own an r-PAIR (same n): lanes 0-31 -> r0=2rp (z-quads 0..31),
// lanes 32-63 -> r1=2rp+1. Same (n,j) for the whole wave -> b-row is
// wave-uniform -> s_load_dwordx16 into SGPRs, v_pk_fma with SGPR broadcast
// (zero LDS/VMEM delivery cost). One dwordx4 store/iter = 2x512 B full lines
// (fill-kernel width). m[32] v4f = 128 VGPR; 1-row-ahead SMEM pipeline.
#define LOAD2(X0, X1, P) \
    asm volatile("s_load_dwordx16 %0, %2, 0x0\n\t" \
                 "s_load_dwordx16 %1, %2, 0x40" \
                 : "=&s"(X0), "=&s"(X1) : "s"(P))
#define WAIT2(X0, X1) \
    asm volatile("s_waitcnt lgkmcnt(0)" : "+s"(X0), "+s"(X1) :: "memory")

__global__ __launch_bounds__(128, 3) void k_out(
    const float* __restrict__ B, const float* __restrict__ M,
    const float* __restrict__ bo, float* __restrict__ out)
{
    const int rp   = blockIdx.x;        // r-pair: r = 2*rp + h
    const int jc   = blockIdx.y;        // 0..1
    const int t    = threadIdx.x;
    const int lane = t & 63;
    const int q    = lane & 31;         // z-quad (z = 4q..4q+3)
    const int h    = lane >> 5;         // 0 -> r0, 1 -> r1
    const int r    = 2 * rp + h;
    const int n    = rp / (LL / 2);     // = r / LL (pairs never straddle n)

    v4f m[CH];
    {
        const v4f* Mr = (const v4f*)(M + (size_t)r * (CH * CZ));  // 32 v4f per d
        #pragma unroll
        for (int d = 0; d < CH; ++d) m[d] = Mr[d * 32 + q];
    }
    const v4f bz = ((const v4f*)bo)[q];

    // wave-uniform j-base (readfirstlane: t>>6 is wave-uniform by construction)
    const int j0 = __builtin_amdgcn_readfirstlane(jc * 192 + (t >> 6) * 96);
    const float* Bj = B + ((size_t)n * LL + j0) * CH;
    v4f* outp = (v4f*)(out + (size_t)r * LL * CZ + (size_t)j0 * CZ) + q;

    v16f bA0, bA1, bB0, bB1;
    LOAD2(bA0, bA1, Bj);                // prologue: row j0 -> A

    #define FMASTORE(V0, V1, ROW) do { \
        v4f a0 = bz, a1 = (v4f)(0.f); \
        _Pragma("unroll") \
        for (int k = 0; k < 16; ++k) { \
            a0 += V0[k] * m[k]; \
            a1 += V1[k] * m[16 + k]; \
        } \
        outp[(size_t)(ROW) * 32] = a0 + a1; \
    } while (0)

    for (int jj = 0; jj < 96; jj += 2) {
        WAIT2(bA0, bA1);
        const float* p1 = Bj + (size_t)(jj + 1) * CH;
        LOAD2(bB0, bB1, p1);
        FMASTORE(bA0, bA1, jj);
        WAIT2(bB0, bB1);
        const float* p2 = (jj + 2 < 96) ? (Bj + (size_t)(jj + 2) * CH) : Bj;
        LOAD2(bA0, bA1, p2);
        FMASTORE(bB0, bB1, jj + 1);
    }
    #undef FMASTORE
}

extern "C" void kernel_launch(void* const* d_in, const int* in_sizes, int n_in,
                              void* d_out, int out_size, void* d_ws, size_t ws_size,
                              hipStream_t stream) {
    const float* s  = (const float*)d_in[0];
    const float* g  = (const float*)d_in[1];
    const float* be = (const float*)d_in[2];
    const float* W1 = (const float*)d_in[3];
    const float* b1 = (const float*)d_in[4];
    const float* W2 = (const float*)d_in[5];
    const float* b2 = (const float*)d_in[6];
    const float* Wo = (const float*)d_in[7];
    const float* bo = (const float*)d_in[8];
    float* out = (float*)d_out;

    const size_t nA = (size_t)NL * CH;
    const size_t nM = (size_t)NL * CH * CZ;
    if (ws_size < (nA * 2 + nM) * sizeof(float)) return;  // fail visibly, no UB

    float* A  = (float*)d_ws;
    float* Bm = A + nA;
    float* M  = Bm + nA;

    k_ln_ab<<<NL, 128, 0, stream>>>(s, g, be, W1, b1, W2, b2, A, Bm);
    k_m   <<<NL / 4, 256, 0, stream>>>(A, Wo, M);
    dim3 gout(NL / 2, 2);
    k_out <<<gout, 128, 0, stream>>>(Bm, M, bo, out);
}

// Round 10
// 94.001 us; speedup vs baseline: 1.2037x; 1.1060x over previous
//
#include <hip/hip_runtime.h>
#include <hip/hip_bf16.h>

#define CS 384
#define CH 32
#define CZ 128
#define LL 384
#define NL 1536   // N*L
#define EPS 1e-5f

typedef float v2f __attribute__((ext_vector_type(2)));
typedef float v4f __attribute__((ext_vector_type(4)));
typedef short s8v __attribute__((ext_vector_type(8)));          // 8 bf16 (MFMA A/B frag)
typedef unsigned short u8s __attribute__((ext_vector_type(8))); // 8 bf16 bits

static __device__ __forceinline__ unsigned short f2bf(float x) {
    unsigned int b = __float_as_uint(x);
    b += 0x7FFFu + ((b >> 16) & 1u);        // round-to-nearest-even
    return (unsigned short)(b >> 16);
}

// ---------------- Kernel 1: LayerNorm + A = sn@W1+b1, B = sn@W2+b2 ------------
__global__ __launch_bounds__(128) void k_ln_ab(
    const float* __restrict__ s, const float* __restrict__ g, const float* __restrict__ be,
    const float* __restrict__ W1, const float* __restrict__ b1,
    const float* __restrict__ W2, const float* __restrict__ b2,
    float* __restrict__ A, float* __restrict__ B)
{
    const int row = blockIdx.x;
    const int t   = threadIdx.x;
    const int wid = t >> 6, lane = t & 63;
    const float* srow = s + (size_t)row * CS;

    __shared__ float sn[CS];
    __shared__ float red[2];
    __shared__ float part[128];

    float x0 = srow[t], x1 = srow[t + 128], x2 = srow[t + 256];

    float p = x0 + x1 + x2;
    #pragma unroll
    for (int o = 32; o > 0; o >>= 1) p += __shfl_down(p, o);
    if (lane == 0) red[wid] = p;
    __syncthreads();
    const float mu = (red[0] + red[1]) * (1.0f / CS);
    __syncthreads();

    float d0 = x0 - mu, d1 = x1 - mu, d2 = x2 - mu;
    float q = d0 * d0 + d1 * d1 + d2 * d2;
    #pragma unroll
    for (int o = 32; o > 0; o >>= 1) q += __shfl_down(q, o);
    if (lane == 0) red[wid] = q;
    __syncthreads();
    const float var = (red[0] + red[1]) * (1.0f / CS);
    const float rstd = rsqrtf(var + EPS);

    sn[t]       = d0 * rstd * g[t]       + be[t];
    sn[t + 128] = d1 * rstd * g[t + 128] + be[t + 128];
    sn[t + 256] = d2 * rstd * g[t + 256] + be[t + 256];
    __syncthreads();

    {
        const int h    = t & 31;
        const int mat  = (t >> 5) & 1;
        const int half = t >> 6;
        const float* W = mat ? W2 : W1;
        float acc = 0.0f;
        const int c0 = half * (CS / 2);
        #pragma unroll 8
        for (int c = c0; c < c0 + CS / 2; ++c)
            acc += sn[c] * W[c * CH + h];
        part[t] = acc;
    }
    __syncthreads();
    if (t < 64) {
        const int h   = t & 31;
        const int mat = t >> 5;
        const float v = part[t] + part[t + 64] + (mat ? b2[h] : b1[h]);
        (mat ? B : A)[(size_t)row * CH + h] = v;
    }
}

// ---------------- Kernel 1b: pack B into bf16 MFMA A-fragments ---------------
// Bf[((n*24 + jt)*64 + l)*8 + e] = bf16( B[n, jt*16 + (l&15), (l>>4)*8 + e] )
__global__ __launch_bounds__(64) void k_packB(
    const float* __restrict__ B, unsigned short* __restrict__ Bf)
{
    const int jt = blockIdx.x;      // 0..23
    const int n  = blockIdx.y;      // 0..3
    const int l  = threadIdx.x;     // 0..63
    const int row = jt * 16 + (l & 15);
    const int g   = l >> 4;
    const float* src = B + ((size_t)(n * LL + row)) * CH + g * 8;
    u8s o;
    #pragma unroll
    for (int e = 0; e < 8; ++e) o[e] = f2bf(src[e]);
    *(u8s*)(Bf + (((size_t)(n * 24 + jt)) * 64 + l) * 8) = o;
}

// ---------------- Kernel 2: M = A@Wo in LDS, emit bf16 MFMA B-frags ----------
// Mf[((r*8 + zt)*64 + l)*8 + e] = bf16( M[r, (l>>4)*8 + e, zt*16 + (l&15)] )
__global__ __launch_bounds__(256, 2) void k_m2(
    const float* __restrict__ A, const float* __restrict__ Wo,
    unsigned short* __restrict__ Mf)
{
    const int t  = threadIdx.x;
    const int r0 = blockIdx.x * 4;
    __shared__ float Al[4][CH];
    __shared__ float Msub[4 * 32 * 128];   // [rr][d][z], 64 KB
    if (t < 128) Al[t >> 5][t & 31] = A[(size_t)(r0 + (t >> 5)) * CH + (t & 31)];
    __syncthreads();

    const v4f* Wo4 = (const v4f*)Wo;       // 1024 v4f per c-row

    #pragma unroll
    for (int it = 0; it < 4; ++it) {
        const int col = t + it * 256;      // col = d*32 + zq
        v4f acc[4];
        #pragma unroll
        for (int r = 0; r < 4; ++r) acc[r] = (v4f)(0.f);
        #pragma unroll 8
        for (int c = 0; c < CH; ++c) {
            const v4f wv = Wo4[(size_t)c * 1024 + col];
            #pragma unroll
            for (int r = 0; r < 4; ++r)
                acc[r] += Al[r][c] * wv;
        }
        #pragma unroll
        for (int r = 0; r < 4; ++r)
            *((v4f*)&Msub[r * 4096 + col * 4]) = acc[r];   // flat = r*4096 + d*128 + zq*4
    }
    __syncthreads();

    #pragma unroll
    for (int i = 0; i < 8; ++i) {
        const int item = t + i * 256;          // 0..2047
        const int l  = item & 63;
        const int zt = (item >> 6) & 7;
        const int rr = item >> 9;
        const int g  = l >> 4;
        const int z  = zt * 16 + (l & 15);
        u8s o;
        #pragma unroll
        for (int e = 0; e < 8; ++e)
            o[e] = f2bf(Msub[rr * 4096 + (g * 8 + e) * 128 + z]);
        *(u8s*)(Mf + (((size_t)(r0 + rr) * 8 + zt) * 64 + l) * 8) = o;
    }
}

// ---------------- Kernel 3: out[r,j,z] via MFMA --------------------------------
// Block = r (256 thr, 4 waves). Wave w: j-tiles {w, w+4, ...} (6) x 8 z-tiles.
// mf[8] (B-frags for all z) live in regs; per j-tile: 1 A-frag load + 8 MFMA.
// C/D layout (HW-verified m89): col = lane&15 (z), row = (lane>>4)*4 + reg (j).
__global__ __launch_bounds__(256, 4) void k_out(
    const unsigned short* __restrict__ Bf, const unsigned short* __restrict__ Mf,
    const float* __restrict__ bo, float* __restrict__ out)
{
    const int r = blockIdx.x;
    const int t = threadIdx.x;
    const int l = t & 63, w = t >> 6;
    const int g = l >> 4, c16 = l & 15;
    const int n = r / LL;

    s8v mf[8];
    {
        const s8v* Mfr = (const s8v*)(Mf + (size_t)r * 8 * 64 * 8);
        #pragma unroll
        for (int zt = 0; zt < 8; ++zt) mf[zt] = Mfr[zt * 64 + l];
    }
    float bz[8];
    #pragma unroll
    for (int zt = 0; zt < 8; ++zt) bz[zt] = bo[zt * 16 + c16];

    const s8v* Bfn = (const s8v*)(Bf + (size_t)n * 24 * 64 * 8);
    float* outb = out + (size_t)r * LL * CZ + (size_t)(g * 4) * CZ + c16;

    for (int jt = w; jt < 24; jt += 4) {
        const s8v af = Bfn[jt * 64 + l];
        float* p = outb + (size_t)jt * 16 * CZ;
        #pragma unroll
        for (int zt = 0; zt < 8; ++zt) {
            v4f d = __builtin_amdgcn_mfma_f32_16x16x32_bf16(af, mf[zt], (v4f)(0.f), 0, 0, 0);
            #pragma unroll
            for (int e = 0; e < 4; ++e)
                p[e * CZ + zt * 16] = d[e] + bz[zt];
        }
    }
}

extern "C" void kernel_launch(void* const* d_in, const int* in_sizes, int n_in,
                              void* d_out, int out_size, void* d_ws, size_t ws_size,
                              hipStream_t stream) {
    const float* s  = (const float*)d_in[0];
    const float* g  = (const float*)d_in[1];
    const float* be = (const float*)d_in[2];
    const float* W1 = (const float*)d_in[3];
    const float* b1 = (const float*)d_in[4];
    const float* W2 = (const float*)d_in[5];
    const float* b2 = (const float*)d_in[6];
    const float* Wo = (const float*)d_in[7];
    const float* bo = (const float*)d_in[8];
    float* out = (float*)d_out;

    // ws layout (bytes): A fp32 [0,196608) | B fp32 [196608,393216)
    //                    | Bf bf16 [393216,491520) | Mf bf16 [491520,+12582912)
    if (ws_size < 491520u + 12582912u) return;  // fail visibly, no UB
    float* A  = (float*)d_ws;
    float* Bm = A + (size_t)NL * CH;
    unsigned short* Bf = (unsigned short*)((char*)d_ws + 393216);
    unsigned short* Mf = (unsigned short*)((char*)d_ws + 491520);

    k_ln_ab<<<NL, 128, 0, stream>>>(s, g, be, W1, b1, W2, b2, A, Bm);
    dim3 gpb(24, 4);
    k_packB<<<gpb, 64, 0, stream>>>(Bm, Bf);
    k_m2  <<<NL / 4, 256, 0, stream>>>(A, Wo, Mf);
    k_out <<<NL, 256, 0, stream>>>(Bf, Mf, bo, out);
}